// Round 5
// baseline (62.978 us; speedup 1.0000x reference)
//
#include <hip/hip_runtime.h>

typedef unsigned short u16;
typedef __attribute__((ext_vector_type(8))) short bf16x8;  // 8 bf16 = 4 VGPRs (MFMA A/B frag)
typedef __attribute__((ext_vector_type(4))) float f32x4;   // MFMA C/D frag

constexpr int   kN    = 8192;
constexpr int   kD    = 256;
constexpr float kInvD = 1.0f / 256.0f;
constexpr float kInv2D = 2.0f / 256.0f;   // 2/D
constexpr float kInvN = 1.0f / 8192.0f;

#define GLOAD_LDS16(gptr, ldsptr)                                                   \
  __builtin_amdgcn_global_load_lds(                                                 \
      (const __attribute__((address_space(1))) unsigned int*)(gptr),                \
      (__attribute__((address_space(3))) unsigned int*)(ldsptr), 16, 0, 0)

// ---------------------------------------------------------------------------
// Kernel 1: prep — f32 -> bf16 convert, packed {sum-of-squares, id} per row,
// zero out. One wave per row (4 rows / 256-thread block).
// ---------------------------------------------------------------------------
__global__ __launch_bounds__(256) void prep_kernel(
    const float* __restrict__ samples, const float* __restrict__ input1,
    u16* __restrict__ bf, float2* __restrict__ sqid, float* __restrict__ out)
{
  const int row  = blockIdx.x * 4 + (threadIdx.x >> 6);
  const int lane = threadIdx.x & 63;

  const float4 v = *(const float4*)(samples + (size_t)row * kD + lane * 4);

  float tmp[4] = {v.x, v.y, v.z, v.w};
  u16 h[4];
#pragma unroll
  for (int i = 0; i < 4; ++i) {
    union { float f; unsigned u; } c;
    c.f = tmp[i];
    unsigned r = c.u + 0x7fffu + ((c.u >> 16) & 1u);
    h[i] = (u16)(r >> 16);
  }
  *(ushort4*)(bf + (size_t)row * kD + lane * 4) = make_ushort4(h[0], h[1], h[2], h[3]);

  float ss = v.x * v.x + v.y * v.y + v.z * v.z + v.w * v.w;
#pragma unroll
  for (int m = 32; m >= 1; m >>= 1) ss += __shfl_xor(ss, m);

  if (lane == 0) {
    sqid[row] = make_float2(ss, input1[row * 32 + 7]);
    out[row]  = 0.0f;
  }
}

// ---------------------------------------------------------------------------
// Kernel 2: 256x256-tile triangle, 8-phase-style pipelined MFMA (m201-like).
// 528 blocks (32x33/2), 512 threads = 8 waves (2 wm x 4 wn), per-wave output
// 128x64 (acc[8][4] f32x4). BK=64, K=256 -> 4 K-tiles, full K-tile double
// buffer in 128 KB dynamic LDS. Per phase (C-quadrant x K=64): 12x
// ds_read_b128 + front-loaded global_load_lds prefetch of K-tile kt+1, raw
// s_barrier (no vmcnt drain), setprio around 16 MFMA, counted vmcnt at
// K-tile boundaries only. XOR-swizzle on staging source + ds_read slot
// (rule #21, proven 0-conflict in R1-R4).
// Epilogue: fold (S-1+eq)^2, LDS cross-wave reduce -> 256 row + 256 col
// atomics per block.
// ---------------------------------------------------------------------------
__global__ __launch_bounds__(512, 2) void simloss_main(
    const u16* __restrict__ bf, const float2* __restrict__ sqid,
    float* __restrict__ out)
{
  extern __shared__ u16 smem[];
  u16* Abuf[2] = {smem, smem + 16384};           // [256][64] each
  u16* Bbuf[2] = {smem + 32768, smem + 49152};   // [256][64] each

  const int tid  = threadIdx.x;
  const int lane = tid & 63;
  const int wid  = tid >> 6;       // wave 0..7
  const int wm   = wid >> 2;       // 0..1  (row half of C)
  const int wn   = wid & 3;        // 0..3  (col quarter of C)
  const int llo  = lane & 15;
  const int lhi  = lane >> 4;

  // triangle decode over 32 tile-rows: tj <= ti; rows I = tj*256, cols J = ti*256
  const int b = blockIdx.x;
  int ti = (int)((sqrtf(8.0f * (float)b + 1.0f) - 1.0f) * 0.5f);
  while ((ti + 1) * (ti + 2) / 2 <= b) ++ti;
  while (ti * (ti + 1) / 2 > b) --ti;
  const int tj = b - ti * (ti + 1) / 2;
  const int i0 = tj * 256;
  const int j0 = ti * 256;
  const bool diag = (ti == tj);

  // stage one 64-row pass of one operand into a K-tile buffer [256][64].
  // dest is linear (wave-uniform base + lane*16B); source column pre-swizzled.
  auto stage64 = [&](u16* dst, int grow0, int rbase, int kcol) {
    const int r   = rbase + (tid >> 3);
    const int sl  = tid & 7;
    const int ksl = sl ^ (r & 7);
    const u16* g  = bf + (size_t)(grow0 + r) * kD + kcol + ksl * 8;
    GLOAD_LDS16(g, dst + r * 64 + sl * 8);
  };

  f32x4 acc[8][4];
#pragma unroll
  for (int mi = 0; mi < 8; ++mi)
#pragma unroll
    for (int ni = 0; ni < 4; ++ni) acc[mi][ni] = {0.f, 0.f, 0.f, 0.f};

  // ---- prologue: stage kt0 -> buf0 (first 8 loads), kt1 -> buf1 (next 8) ----
#pragma unroll
  for (int h = 0; h < 4; ++h) stage64(Abuf[0], i0, h * 64, 0);
#pragma unroll
  for (int h = 0; h < 4; ++h) stage64(Bbuf[0], j0, h * 64, 0);
#pragma unroll
  for (int h = 0; h < 4; ++h) stage64(Abuf[1], i0, h * 64, 64);
#pragma unroll
  for (int h = 0; h < 4; ++h) stage64(Bbuf[1], j0, h * 64, 64);
  asm volatile("s_waitcnt vmcnt(8)" ::: "memory");   // kt0 retired
  __builtin_amdgcn_s_barrier();

  // ---- main loop: 4 K-tiles x 4 quadrant-phases ----
#pragma unroll
  for (int kt = 0; kt < 4; ++kt) {
    const u16* Ac = Abuf[kt & 1];
    const u16* Bc = Bbuf[kt & 1];
#pragma unroll
    for (int q = 0; q < 4; ++q) {
      const int mq = q >> 1, nq = q & 1;
      // 12 x ds_read_b128 for this quadrant (compiler tracks lgkm deps)
      bf16x8 a[4][2], bv[2][2];
#pragma unroll
      for (int i = 0; i < 4; ++i) {
        const int ra = wm * 128 + (mq * 4 + i) * 16 + llo;
#pragma unroll
        for (int ks = 0; ks < 2; ++ks) {
          const int slot = (ks * 4 + lhi) ^ (ra & 7);
          a[i][ks] = *(const bf16x8*)(Ac + ra * 64 + slot * 8);
        }
      }
#pragma unroll
      for (int j = 0; j < 2; ++j) {
        const int rb = wn * 64 + (nq * 2 + j) * 16 + llo;
#pragma unroll
        for (int ks = 0; ks < 2; ++ks) {
          const int slot = (ks * 4 + lhi) ^ (rb & 7);
          bv[j][ks] = *(const bf16x8*)(Bc + rb * 64 + slot * 8);
        }
      }
      // front-loaded prefetch of K-tile kt+1 into the just-freed buffer
      // (kt=1 stages kt2 -> buf0; kt=2 stages kt3 -> buf1)
      if (kt == 1 || kt == 2) {
        const int skt = kt + 1;
        if (q == 0) {
#pragma unroll
          for (int h = 0; h < 4; ++h) stage64(Abuf[skt & 1], i0, h * 64, skt * 64);
        } else if (q == 1) {
#pragma unroll
          for (int h = 0; h < 4; ++h) stage64(Bbuf[skt & 1], j0, h * 64, skt * 64);
        }
      }
      __builtin_amdgcn_s_barrier();
      __builtin_amdgcn_s_setprio(1);
#pragma unroll
      for (int i = 0; i < 4; ++i)
#pragma unroll
        for (int j = 0; j < 2; ++j)
#pragma unroll
          for (int ks = 0; ks < 2; ++ks)
            acc[mq * 4 + i][nq * 2 + j] = __builtin_amdgcn_mfma_f32_16x16x32_bf16(
                a[i][ks], bv[j][ks], acc[mq * 4 + i][nq * 2 + j], 0, 0, 0);
      __builtin_amdgcn_s_setprio(0);
      if (q == 3 && kt < 3)
        asm volatile("s_waitcnt vmcnt(0)" ::: "memory");  // next K-tile landed (issued >=2 phases ago)
      __builtin_amdgcn_s_barrier();
    }
  }

  // ---- epilogue: t = (S - 1 + eq)^2; LDS cross-wave reduce; 512 atomics ----
  float sqjm1[4], idj[4];
#pragma unroll
  for (int ni = 0; ni < 4; ++ni) {
    const float2 p = sqid[j0 + wn * 64 + ni * 16 + llo];
    sqjm1[ni] = p.x * kInvD - 1.0f;
    idj[ni]   = p.y;
  }

  float* rowpart = (float*)smem;            // [4 wn][256]
  float* colpart = (float*)smem + 1024;     // [2 wm][256]
  float colacc[4] = {};

#pragma unroll
  for (int mi = 0; mi < 8; ++mi) {
    float sqi_s[4], idi[4];
#pragma unroll
    for (int r = 0; r < 4; ++r) {
      const float2 p = sqid[i0 + wm * 128 + mi * 16 + lhi * 4 + r];
      sqi_s[r] = p.x * kInvD;
      idi[r]   = p.y;
    }
    float racc[4] = {};
#pragma unroll
    for (int ni = 0; ni < 4; ++ni)
#pragma unroll
      for (int r = 0; r < 4; ++r) {
        float s1 = fmaf(acc[mi][ni][r], -kInv2D, sqi_s[r] + sqjm1[ni]);
        s1 += (idi[r] == idj[ni]) ? 1.0f : 0.0f;
        const float t = s1 * s1;
        racc[r] += t;
        colacc[ni] += t;
      }
#pragma unroll
    for (int r = 0; r < 4; ++r) {
      float v = racc[r];
      v += __shfl_xor(v, 1);
      v += __shfl_xor(v, 2);
      v += __shfl_xor(v, 4);
      v += __shfl_xor(v, 8);
      if (llo == 0)
        rowpart[wn * 256 + wm * 128 + mi * 16 + lhi * 4 + r] = v;
    }
  }
#pragma unroll
  for (int ni = 0; ni < 4; ++ni) {
    float v = colacc[ni];
    v += __shfl_xor(v, 16);
    v += __shfl_xor(v, 32);
    if (lhi == 0)
      colpart[wm * 256 + wn * 64 + ni * 16 + llo] = v;
  }
  __syncthreads();

  if (tid < 256) {
    const float s = rowpart[tid] + rowpart[256 + tid] + rowpart[512 + tid] + rowpart[768 + tid];
    atomicAdd(&out[i0 + tid], s * kInvN);
  } else if (!diag) {
    const int c = tid - 256;
    const float s = colpart[c] + colpart[256 + c];
    atomicAdd(&out[j0 + c], s * kInvN);
  }
}

// ---------------------------------------------------------------------------
extern "C" void kernel_launch(void* const* d_in, const int* in_sizes, int n_in,
                              void* d_out, int out_size, void* d_ws, size_t ws_size,
                              hipStream_t stream) {
  const float* samples = (const float*)d_in[0];
  const float* input1  = (const float*)d_in[1];
  float* out = (float*)d_out;

  char* ws = (char*)d_ws;
  u16*    bf   = (u16*)ws;                                  // 4 MB bf16 samples
  float2* sqid = (float2*)(ws + (size_t)4 * 1024 * 1024);   // 64 KB {sq, id}

  // allow 128 KB dynamic LDS (idempotent; not a stream op, capture-safe)
  hipFuncSetAttribute(reinterpret_cast<const void*>(&simloss_main),
                      hipFuncAttributeMaxDynamicSharedMemorySize, 131072);

  prep_kernel<<<kN / 4, 256, 0, stream>>>(samples, input1, bf, sqid, out);
  simloss_main<<<32 * 33 / 2, 512, 131072, stream>>>(bf, sqid, out);
}